// Round 7
// baseline (38.771 us; speedup 1.0000x reference)
//
#include <hip/hip_runtime.h>
#include <math.h>

// Problem constants: B=4, H=W=64, M=8, K=64
#define HW  4096
#define KK  64
#define BLK 256              // 4 waves per workgroup
#define BLOCKS_PER_WG 16     // 4 waves * 4 blocks/wave

__device__ __forceinline__ unsigned umin32(unsigned a, unsigned b) { return a < b ? a : b; }

__device__ __forceinline__ float softplusf(float x) {
    return fmaxf(x, 0.0f) + log1pf(expf(-fabsf(x)));
}

// Layout: wave = 4 groups x 16 lanes. Group g owns block bid = wv*4+g.
// Lane q of a group owns slots q*4+u (u=0..3). Greedy argmin per step:
// 4 in-register costs -> 3 v_min_u32 -> 4-level ds_swizzle XOR butterfly
// within the 16-lane group (xor 1,2,4,8 stays inside the group). Key =
// (float bits of cost & ~63) | slot_id: u32 min == cost argmin with
// first-index tie-break (verified absmax 0.0 in rounds 2-5 at 64-lane).
__global__ __launch_bounds__(BLK) void assign_loss_kernel(
    const float4* __restrict__ ps4,   // pred_scores  viewed as float4
    const float4* __restrict__ po4,   // pred_offsets viewed as float4
    const int4*   __restrict__ tgt4,  // target       viewed as int4
    float* __restrict__ pobj,
    float* __restrict__ ploc,
    int*   __restrict__ pnp)
{
    const int lane = threadIdx.x & 63;
    const int wib  = threadIdx.x >> 6;
    const int wv   = blockIdx.x * 4 + wib;     // wave id (4096 total)
    const int g    = lane >> 4;                // group (block within wave)
    const int q    = lane & 15;
    const int bid  = wv * 4 + g;               // (b,n) block id, 0..16383
    const int b    = bid >> 12;                // / HW
    const int n    = bid & (HW - 1);
    const int h    = n >> 6, w = n & 63;

    // coalesced vector loads: slots q*4 .. q*4+3
    const float4 sc = ps4[bid * 16 + q];
    const float4 pa = po4[bid * 32 + q * 2];
    const float4 pb = po4[bid * 32 + q * 2 + 1];
    // target cells q*4..q*4+3 of this block: row h*8+(q>>1), cols w*8+(q&1)*4+0..3
    const int4 tv = tgt4[(b * 512 + h * 8 + (q >> 1)) * 128 + w * 2 + (q & 1)];

    float p0[4] = {pa.x, pa.z, pb.x, pb.z};
    float p1[4] = {pa.y, pa.w, pb.y, pb.w};
    float s[4]  = {sc.x, sc.y, sc.z, sc.w};

    const int bbit[4] = {tv.x > 0, tv.y > 0, tv.z > 0, tv.w > 0};
    int cnt = bbit[0] + bbit[1] + bbit[2] + bbit[3];   // each cell counted once

    // per-group 16-bit mask words: wm[v] bit q' <=> cell q'*4+v positive
    const unsigned long long BL0 = __ballot(bbit[0]);
    const unsigned long long BL1 = __ballot(bbit[1]);
    const unsigned long long BL2 = __ballot(bbit[2]);
    const unsigned long long BL3 = __ballot(bbit[3]);
    const int sh = g * 16;
    unsigned wm[4] = {
        (unsigned)(BL0 >> sh) & 0xFFFFu, (unsigned)(BL1 >> sh) & 0xFFFFu,
        (unsigned)(BL2 >> sh) & 0xFFFFu, (unsigned)(BL3 >> sh) & 0xFFFFu };

    float sig[4], cl[4], locl[4];
    #pragma unroll
    for (int u = 0; u < 4; ++u) {
        sig[u]  = 1.0f / (1.0f + expf(-s[u]));
        cl[u]   = sqrtf(sqrtf(1.0f - sig[u]));   // order-equiv class factor ^0.25
        locl[u] = 0.0f;
    }

    const float FINF = __builtin_huge_valf();

    // greedy over cells t = qt*4+v in raster order (matches reference's
    // stable positives-first ordering). Branch-free: dead cells are gated
    // by 'live' (adj -> 0xFFFFFFFF never matches a real key).
    for (int qt = 0; qt < 16; ++qt) {
        const float by  = (float)(qt >> 1) * 0.125f - 0.4375f;   // exact
        const float bx0 = (qt & 1) ? 0.0625f : -0.4375f;         // exact
        #pragma unroll
        for (int v = 0; v < 4; ++v) {
            const float bxv = bx0 + 0.125f * (float)v;           // exact
            const unsigned live = wm[v] & 1u;
            float l[4]; unsigned k[4];
            #pragma unroll
            for (int u = 0; u < 4; ++u) {
                l[u] = fabsf(p0[u] - by) + fabsf(p1[u] - bxv);
                k[u] = (__float_as_uint(l[u] * cl[u]) & ~63u) | (unsigned)(q * 4 + u);
            }
            unsigned x = umin32(umin32(k[0], k[1]), umin32(k[2], k[3]));
            // XOR butterfly within the 16-lane group (LDS crossbar pipe)
            x = umin32(x, (unsigned)__builtin_amdgcn_ds_swizzle((int)x, 0x041F));
            x = umin32(x, (unsigned)__builtin_amdgcn_ds_swizzle((int)x, 0x081F));
            x = umin32(x, (unsigned)__builtin_amdgcn_ds_swizzle((int)x, 0x101F));
            x = umin32(x, (unsigned)__builtin_amdgcn_ds_swizzle((int)x, 0x201F));
            const unsigned adj = x | (live - 1u);   // live? groupmin : 0xFFFFFFFF
            #pragma unroll
            for (int u = 0; u < 4; ++u) {
                const bool win = (k[u] == adj);     // at most one lane/slot
                cl[u]   = win ? FINF : cl[u];       // exclude (cost -> inf/NaN keys)
                locl[u] = win ? l[u] : locl[u];     // each slot wins <= once
            }
        }
        wm[0] >>= 1; wm[1] >>= 1; wm[2] >>= 1; wm[3] >>= 1;
    }

    // focal + loc losses
    float focal = 0.0f, locs = 0.0f;
    #pragma unroll
    for (int u = 0; u < 4; ++u) {
        const bool asg = (cl[u] > 1e30f);
        const float ce  = asg ? softplusf(-s[u]) : softplusf(s[u]);
        const float p_t = asg ? sig[u] : (1.0f - sig[u]);
        const float om  = 1.0f - p_t;
        focal += ce * om * om * (asg ? 0.6f : 0.4f);
        locs  += locl[u];                      // 0 unless assigned
    }

    // wave-level sums
    #pragma unroll
    for (int o = 32; o; o >>= 1) {
        focal += __shfl_xor(focal, o, 64);
        locs  += __shfl_xor(locs,  o, 64);
        cnt   += __shfl_xor(cnt,   o, 64);
    }

    __shared__ float sobj[4], sloc[4];
    __shared__ int   snp[4];
    if (lane == 0) { sobj[wib] = focal; sloc[wib] = locs; snp[wib] = cnt; }
    __syncthreads();
    if (threadIdx.x == 0) {
        float o = 0.0f, l = 0.0f; int np = 0;
        #pragma unroll
        for (int t = 0; t < 4; ++t) { o += sobj[t]; l += sloc[t]; np += snp[t]; }
        pobj[blockIdx.x] = o;
        ploc[blockIdx.x] = l;
        pnp [blockIdx.x] = np;
    }
}

__global__ __launch_bounds__(256) void finalize_kernel(
    const float* __restrict__ pobj,
    const float* __restrict__ ploc,
    const int*   __restrict__ pnp,
    int nb, float* __restrict__ out)
{
    __shared__ double so[256], sl[256];
    __shared__ long long sn[256];
    double o = 0.0, l = 0.0;
    long long np = 0;
    for (int i = threadIdx.x; i < nb; i += 256) {
        o  += (double)pobj[i];
        l  += (double)ploc[i];
        np += (long long)pnp[i];
    }
    so[threadIdx.x] = o; sl[threadIdx.x] = l; sn[threadIdx.x] = np;
    __syncthreads();
    for (int st = 128; st; st >>= 1) {
        if (threadIdx.x < st) {
            so[threadIdx.x] += so[threadIdx.x + st];
            sl[threadIdx.x] += sl[threadIdx.x + st];
            sn[threadIdx.x] += sn[threadIdx.x + st];
        }
        __syncthreads();
    }
    if (threadIdx.x == 0) {
        long long npos = sn[0] > 1 ? sn[0] : 1;
        out[0] = (float)((so[0] + 10.0 * sl[0]) / (double)npos);
    }
}

extern "C" void kernel_launch(void* const* d_in, const int* in_sizes, int n_in,
                              void* d_out, int out_size, void* d_ws, size_t ws_size,
                              hipStream_t stream) {
    const float4* ps4  = (const float4*)d_in[0];
    const float4* po4  = (const float4*)d_in[1];
    const int4*   tgt4 = (const int4*)d_in[2];

    const int total_blocks = in_sizes[0] / KK;            // 16384
    const int nwg = total_blocks / BLOCKS_PER_WG;         // 1024

    float* pobj = (float*)d_ws;
    float* ploc = pobj + nwg;
    int*   pnp  = (int*)(ploc + nwg);

    assign_loss_kernel<<<nwg, BLK, 0, stream>>>(ps4, po4, tgt4, pobj, ploc, pnp);
    finalize_kernel<<<1, 256, 0, stream>>>(pobj, ploc, pnp, nwg, (float*)d_out);
}

// Round 8
// 34.433 us; speedup vs baseline: 1.1260x; 1.1260x over previous
//
#include <hip/hip_runtime.h>
#include <math.h>

// Problem constants: B=4, H=W=64, M=8, K=64
#define HW  4096
#define KK  64
#define WPB 4
#define BLK (WPB*64)

__device__ __forceinline__ float softplusf(float x) {
    return fmaxf(x, 0.0f) + log1pf(expf(-fabsf(x)));
}

// 64-lane min via fused v_min_u32_dpp shr-chain (verified rounds 2/4/5,
// absmax 0.0). s_nop 1 supplies the 2 required wait states between a VALU
// write and a DPP read of the same VGPR. Full min lands in lane 63.
__device__ __forceinline__ unsigned wave_min_u32(unsigned x) {
    asm("s_nop 1\n\t"
        "v_min_u32_dpp %0, %0, %0 row_shr:1  row_mask:0xf bank_mask:0xf\n\t"
        "s_nop 1\n\t"
        "v_min_u32_dpp %0, %0, %0 row_shr:2  row_mask:0xf bank_mask:0xf\n\t"
        "s_nop 1\n\t"
        "v_min_u32_dpp %0, %0, %0 row_shr:4  row_mask:0xf bank_mask:0xf\n\t"
        "s_nop 1\n\t"
        "v_min_u32_dpp %0, %0, %0 row_shr:8  row_mask:0xf bank_mask:0xf\n\t"
        "s_nop 1\n\t"
        "v_min_u32_dpp %0, %0, %0 row_bcast:15 row_mask:0xf bank_mask:0xf\n\t"
        "s_nop 1\n\t"
        "v_min_u32_dpp %0, %0, %0 row_bcast:31 row_mask:0xf bank_mask:0xf\n\t"
        "s_nop 1"
        : "+v"(x));
    return (unsigned)__builtin_amdgcn_readlane((int)x, 63);
}

__global__ __launch_bounds__(BLK) void assign_loss_kernel(
    const float*  __restrict__ ps,     // [B,HW,K]
    const float2* __restrict__ po,     // [B,HW,K] float2
    const int*    __restrict__ tgt,    // [B,512,512]
    float* __restrict__ pobj,
    float* __restrict__ ploc,
    int*   __restrict__ pnp)
{
    const int lane = threadIdx.x & 63;
    const int wib  = threadIdx.x >> 6;
    const int wid  = blockIdx.x * WPB + wib;   // (b,n) block, grid is exact

    const int b = wid >> 12;                   // / HW
    const int n = wid & (HW - 1);
    const int h = n >> 6, w = n & 63;

    const int base = wid * KK + lane;
    const float  s  = ps[base];
    const float2 pv = po[base];
    const float po0 = pv.x, po1 = pv.y;

    const int ti = lane >> 3, tj = lane & 7;
    const int tv = tgt[((b * 512) + h * 8 + ti) * 512 + (w * 8 + tj)] > 0;
    const unsigned long long mask = __ballot(tv);
    const int npos = __popcll(mask);

    const float sig = 1.0f / (1.0f + expf(-s));
    const float cl  = sqrtf(sqrtf(1.0f - sig));   // order-equiv ^0.25 factor

    // --- software-pipelined greedy assignment ---------------------------
    // Exclusion via per-lane 'dead' OR-mask (0xFFFFFFFF > any finite key),
    // so cl never changes and step t+1's key computation is independent of
    // step t's winner -> it schedules into the DPP chain's latency shadow.
    unsigned long long m = mask;
    int t0 = (int)__ffsll(m) - 1;                 // garbage if m==0 (unused)
    float by = (float)(t0 >> 3) * 0.125f - 0.4375f;
    float bx = (float)(t0 & 7)  * 0.125f - 0.4375f;
    float loc_c = fabsf(po0 - by) + fabsf(po1 - bx);
    unsigned key_c = (__float_as_uint(loc_c * cl) & ~63u) | (unsigned)lane;

    unsigned dead = 0u;
    float locl = 0.0f;

    while (m) {
        const unsigned long long m2 = m & (m - 1);
        // next step (independent of this step's outcome)
        const int t2 = (int)__ffsll(m2) - 1;      // garbage when m2==0: unused
        const float by2 = (float)(t2 >> 3) * 0.125f - 0.4375f;
        const float bx2 = (float)(t2 & 7)  * 0.125f - 0.4375f;
        const float loc_n = fabsf(po0 - by2) + fabsf(po1 - bx2);
        const unsigned key_n =
            (__float_as_uint(loc_n * cl) & ~63u) | (unsigned)lane;

        // resolve current step
        const unsigned kc = key_c | dead;
        const unsigned mn = wave_min_u32(kc);     // uniform (SGPR)
        const unsigned winner = mn & 63u;         // SALU
        const bool win = ((unsigned)lane == winner);
        dead = win ? 0xFFFFFFFFu : dead;
        locl = win ? loc_c : locl;                // each lane wins <= once

        key_c = key_n; loc_c = loc_n; m = m2;
    }

    // --- losses ---------------------------------------------------------
    const bool assigned = (dead != 0u);
    const float ce  = assigned ? softplusf(-s) : softplusf(s);
    const float p_t = assigned ? sig : (1.0f - sig);
    const float om  = 1.0f - p_t;
    float focal = ce * om * om * (assigned ? 0.6f : 0.4f);
    if (!assigned) locl = 0.0f;

    float locs = locl;
    int   cnt  = npos;   // wave-uniform
    #pragma unroll
    for (int o = 32; o; o >>= 1) {
        focal += __shfl_xor(focal, o, 64);
        locs  += __shfl_xor(locs,  o, 64);
    }

    __shared__ float sobj[WPB], sloc[WPB];
    __shared__ int   snp[WPB];
    if (lane == 0) { sobj[wib] = focal; sloc[wib] = locs; snp[wib] = cnt; }
    __syncthreads();
    if (threadIdx.x == 0) {
        float o = 0.0f, l = 0.0f; int np = 0;
        #pragma unroll
        for (int q = 0; q < WPB; ++q) { o += sobj[q]; l += sloc[q]; np += snp[q]; }
        pobj[blockIdx.x] = o;
        ploc[blockIdx.x] = l;
        pnp [blockIdx.x] = np;
    }
}

__global__ __launch_bounds__(256) void finalize_kernel(
    const float* __restrict__ pobj,
    const float* __restrict__ ploc,
    const int*   __restrict__ pnp,
    int nb, float* __restrict__ out)
{
    __shared__ double so[256], sl[256];
    __shared__ long long sn[256];
    double o = 0.0, l = 0.0;
    long long np = 0;
    for (int i = threadIdx.x; i < nb; i += 256) {
        o  += (double)pobj[i];
        l  += (double)ploc[i];
        np += (long long)pnp[i];
    }
    so[threadIdx.x] = o; sl[threadIdx.x] = l; sn[threadIdx.x] = np;
    __syncthreads();
    for (int st = 128; st; st >>= 1) {
        if (threadIdx.x < st) {
            so[threadIdx.x] += so[threadIdx.x + st];
            sl[threadIdx.x] += sl[threadIdx.x + st];
            sn[threadIdx.x] += sn[threadIdx.x + st];
        }
        __syncthreads();
    }
    if (threadIdx.x == 0) {
        long long npos = sn[0] > 1 ? sn[0] : 1;
        out[0] = (float)((so[0] + 10.0 * sl[0]) / (double)npos);
    }
}

extern "C" void kernel_launch(void* const* d_in, const int* in_sizes, int n_in,
                              void* d_out, int out_size, void* d_ws, size_t ws_size,
                              hipStream_t stream) {
    const float*  ps  = (const float*)d_in[0];
    const float2* po  = (const float2*)d_in[1];
    const int*    tgt = (const int*)d_in[2];

    const int total_blocks = in_sizes[0] / KK;          // 16384
    const int nwg = total_blocks / WPB;                 // 4096

    float* pobj = (float*)d_ws;
    float* ploc = pobj + nwg;
    int*   pnp  = (int*)(ploc + nwg);

    assign_loss_kernel<<<nwg, BLK, 0, stream>>>(ps, po, tgt, pobj, ploc, pnp);
    finalize_kernel<<<1, 256, 0, stream>>>(pobj, ploc, pnp, nwg, (float*)d_out);
}